// Round 5
// baseline (229.862 us; speedup 1.0000x reference)
//
#include <hip/hip_runtime.h>

// LIF forward: x [B=32, T=16, N=65536] f32, thresh scalar f32 -> spikes [B,T,N] f32
//   mem = mem*TAU + x[t];  spike = (mem > thresh);  mem = spike ? 0 : mem;
//
// R1: latency-bound, VGPR=20 -> compiler sinks loads next to uses, ~2 in flight,
//     2.5 TB/s. R2: source-level preload array did NOT stop the scheduler from
//     re-sinking the loads (SSA; pressure-aware sched) -> same ~75-80 us.
// R3: __builtin_amdgcn_sched_barrier(0) between preload and compute pins all
//     16 global_load_dwordx2 BEFORE any compute: 32 data VGPRs live across the
//     barrier, counted vmcnt waits, 8 KB in flight per wave. float2 keeps
//     VGPR < 64 => 8 waves/SIMD.

#define TAU 0.25f

typedef float f32x2 __attribute__((ext_vector_type(2)));

__global__ __launch_bounds__(256) void lif_fwd_kernel(
    const f32x2* __restrict__ x,
    const float* __restrict__ thresh,
    f32x2* __restrict__ out)
{
    constexpr int T  = 16;
    constexpr int N2 = 65536 / 2;   // 32768 float2 per (b,t) row

    const int gid = blockIdx.x * blockDim.x + threadIdx.x;  // 0 .. B*N2-1
    const int b   = gid >> 15;          // gid / N2
    const int n2  = gid & (N2 - 1);     // gid % N2

    const float th = thresh[0];

    const size_t base = (size_t)b * T * N2 + n2;
    const f32x2* xp = x   + base;
    f32x2*       op = out + base;

    // Preload all T slices: 16 independent loads.
    f32x2 xt[T];
#pragma unroll
    for (int t = 0; t < T; ++t)
        xt[t] = xp[(size_t)t * N2];

    // Hard scheduling fence: nothing moves across. Forces all 16 loads to
    // issue before any compute -> real memory-level parallelism.
    __builtin_amdgcn_sched_barrier(0);

    f32x2 mem = {0.f, 0.f};

#pragma unroll
    for (int t = 0; t < T; ++t) {
        mem.x = mem.x * TAU + xt[t].x;
        mem.y = mem.y * TAU + xt[t].y;

        const bool px = mem.x > th;
        const bool py = mem.y > th;

        f32x2 s;
        s.x = px ? 1.f : 0.f;
        s.y = py ? 1.f : 0.f;

        mem.x = px ? 0.f : mem.x;
        mem.y = py ? 0.f : mem.y;

        // Output is never re-read: non-temporal keeps L2/L3 for the x stream.
        __builtin_nontemporal_store(s, &op[(size_t)t * N2]);
    }
}

extern "C" void kernel_launch(void* const* d_in, const int* in_sizes, int n_in,
                              void* d_out, int out_size, void* d_ws, size_t ws_size,
                              hipStream_t stream)
{
    const float* x      = (const float*)d_in[0];
    const float* thresh = (const float*)d_in[1];
    float*       out    = (float*)d_out;

    // total = B*T*N = 33,554,432 ; threads = B*N/2 = total/(16*2) = 1,048,576
    const int total   = in_sizes[0];
    const int threads = total / (16 * 2);
    const int block   = 256;
    const int grid    = threads / block;   // 4096 blocks

    lif_fwd_kernel<<<grid, block, 0, stream>>>(
        (const f32x2*)x, thresh, (f32x2*)out);
}